// Round 5
// baseline (537.734 us; speedup 1.0000x reference)
//
#include <hip/hip_runtime.h>
#include <math.h>

// DiscriminativeLoss: N=1e6 x D=32 fp32, K=64, scalar out.
// R5: (a) pass1 LDS-tiled: coalesced stream of each 256-pt tile into LDS
// (issued before sort so HBM latency hides under histogram/scan/scatter),
// divergent gather now hits LDS not HBM; source-side octet swizzle keeps
// LDS reads conflict-free. (b) partial sums via atomicAdd into 8 LLC slice
// accumulators + last-block finisher computes means (kills part1/reduce1/
// mean kernels). (c) pass2 absorbs final via last-block; 2-point unroll.
// Graph: memset + pass1 + pass2 only.

#define EPS_F 1e-8f
constexpr int D  = 32;
constexpr int K  = 64;
constexpr int T1 = 256;                  // points per pass1 tile/block
constexpr int SL = 8;                    // accumulation slices
constexpr int SLSTRIDE = K * D + K;      // 2112 floats per slice
constexpr int NBLK2 = 2048;

// ws layout (float index):
constexpr int A_RACC  = SL * SLSTRIDE;           // 16896: pass2 slice raccs
constexpr int A_CNT   = A_RACC + SL;             // 16904: 2 int counters
constexpr int A_MEANS = A_CNT + 2;               // 16906: K*D means
constexpr int A_ICNT  = A_MEANS + K * D;         // +K icnt
constexpr int ZERO_BYTES = (A_CNT + 2) * 4;      // memset through counters

// ---------------- pass 1: LDS-tiled segment sums + last-block means --------
__global__ __launch_bounds__(256) void pass1_kernel(
    const float* __restrict__ feat, const int* __restrict__ lab,
    float* __restrict__ ws, int N, int ntiles)
{
    __shared__ float          s_tile[T1 * D];    // 32 KB, octet-swizzled
    __shared__ int            s_lab[T1];
    __shared__ unsigned short s_idx[T1];
    __shared__ int            s_hist[K], s_pref[K], s_cur[K];
    __shared__ int            s_flag;

    const int tid = threadIdx.x;
    const long long base = (long long)blockIdx.x * T1;
    int npts = (int)((long long)N - base);
    if (npts > T1) npts = T1;
    const int tbytes = npts * 128;

    // issue tile loads into regs NOW (swizzled source, linear LDS dest);
    // HBM latency hides under the sort phases below.
    float4 st[8];
    const char* fbase = (const char*)(feat + base * D);
    #pragma unroll
    for (int j = 0; j < 8; j++) {
        const int o = j * 4096 + tid * 16;       // linear LDS byte offset
        if (o < tbytes) {
            const int r = o >> 7, slot = (o >> 5) & 3, rem = o & 31;
            const int gof = r * 128 + (((slot - r) & 3) << 5) + rem;
            st[j] = *(const float4*)(fbase + gof);
        }
    }

    if (tid < K) s_hist[tid] = 0;
    __syncthreads();
    int myl = -1;
    if (tid < npts) {
        myl = lab[base + tid];
        s_lab[tid] = myl;
        atomicAdd(&s_hist[myl], 1);
    }
    __syncthreads();
    if (tid < 64) {                              // exclusive scan, wave 0
        const int h = s_hist[tid];
        int v = h;
        for (int off = 1; off < 64; off <<= 1) {
            const int up = __shfl_up(v, off);
            if (tid >= off) v += up;
        }
        s_pref[tid] = v - h;
        s_cur[tid]  = v - h;
    }
    __syncthreads();
    if (tid < npts) {
        const int pos = atomicAdd(&s_cur[myl], 1);
        s_idx[pos] = (unsigned short)tid;
    }
    #pragma unroll
    for (int j = 0; j < 8; j++) {                // land the tile in LDS
        const int o = j * 4096 + tid * 16;
        if (o < tbytes) *(float4*)((char*)s_tile + o) = st[j];
    }
    __syncthreads();

    // accumulate from LDS: thread owns (cluster k, octet q = 8 dims)
    const int k = tid >> 2, q = tid & 3;
    const int start = s_pref[k], len = s_hist[k];
    float4 a0 = {0.f,0.f,0.f,0.f}, a1 = {0.f,0.f,0.f,0.f};
    int i = 0;
    for (; i + 2 <= len; i += 2) {
        const int i0 = s_idx[start + i], i1 = s_idx[start + i + 1];
        const int f0 = i0 * 32 + (((q + i0) & 3) << 3);
        const int f1 = i1 * 32 + (((q + i1) & 3) << 3);
        const float4 x0 = *(const float4*)&s_tile[f0];
        const float4 y0 = *(const float4*)&s_tile[f0 + 4];
        const float4 x1 = *(const float4*)&s_tile[f1];
        const float4 y1 = *(const float4*)&s_tile[f1 + 4];
        a0.x += x0.x + x1.x; a0.y += x0.y + x1.y;
        a0.z += x0.z + x1.z; a0.w += x0.w + x1.w;
        a1.x += y0.x + y1.x; a1.y += y0.y + y1.y;
        a1.z += y0.z + y1.z; a1.w += y0.w + y1.w;
    }
    if (i < len) {
        const int i0 = s_idx[start + i];
        const int f0 = i0 * 32 + (((q + i0) & 3) << 3);
        const float4 x0 = *(const float4*)&s_tile[f0];
        const float4 y0 = *(const float4*)&s_tile[f0 + 4];
        a0.x += x0.x; a0.y += x0.y; a0.z += x0.z; a0.w += x0.w;
        a1.x += y0.x; a1.y += y0.y; a1.z += y0.z; a1.w += y0.w;
    }

    // slice accumulation at LLC (device-scope atomics = coherent)
    float* sl = ws + (blockIdx.x & (SL - 1)) * SLSTRIDE;
    const int cb = k * 32 + q * 8;
    atomicAdd(&sl[cb + 0], a0.x); atomicAdd(&sl[cb + 1], a0.y);
    atomicAdd(&sl[cb + 2], a0.z); atomicAdd(&sl[cb + 3], a0.w);
    atomicAdd(&sl[cb + 4], a1.x); atomicAdd(&sl[cb + 5], a1.y);
    atomicAdd(&sl[cb + 6], a1.z); atomicAdd(&sl[cb + 7], a1.w);
    if (tid < K) atomicAdd(&sl[K * D + tid], (float)s_hist[tid]);

    __syncthreads();                             // drains all waves' vmcnt
    if (tid == 0) {
        __threadfence();                         // release
        s_flag = atomicAdd((int*)(ws + A_CNT), 1);
    }
    __syncthreads();
    if (s_flag != ntiles - 1) return;

    // last block: slices -> means, icnt
    __threadfence();                             // acquire (invalidate caches)
    float* means = ws + A_MEANS;
    float* icnt  = ws + A_ICNT;
    for (int e = tid; e < K * D; e += 256) {
        const int kk = e >> 5;
        float s = 0.f, c = 0.f;
        for (int z = 0; z < SL; z++) {
            s += ws[z * SLSTRIDE + e];
            c += ws[z * SLSTRIDE + K * D + kk];
        }
        means[e] = s / fmaxf(c, 1.0f);
    }
    if (tid < K) {
        float c = 0.f;
        for (int z = 0; z < SL; z++) c += ws[z * SLSTRIDE + K * D + tid];
        icnt[tid] = 1.0f / fmaxf(c, 1.0f);
    }
}

// ---------------- pass 2: hinge^2*icnt + last-block final ------------------
__global__ __launch_bounds__(256) void pass2_kernel(
    const float* __restrict__ feat, const int* __restrict__ lab,
    float* __restrict__ ws, float* __restrict__ out, int N)
{
    __shared__ float s_red[256];
    __shared__ float s_m[K * D];
    __shared__ int   s_flag;
    const float* means = ws + A_MEANS;
    const float* icnt  = ws + A_ICNT;
    const int tid = threadIdx.x;
    const int sub = tid & 7, g = tid >> 3;       // g in [0,32)
    float racc = 0.f;
    const long long stride = (long long)NBLK2 * 64;
    for (long long p0 = (long long)blockIdx.x * 64; p0 < N; p0 += stride) {
        const long long pa = p0 + g, pb = p0 + 32 + g;
        // issue both points' independent load chains together (2x MLP)
        float4 fa, fb, ma, mb; int la = 0, lb = 0;
        const bool va = (pa < N), vb = (pb < N);
        if (va) { la = lab[pa]; fa = *(const float4*)(feat + pa * D + sub * 4); }
        if (vb) { lb = lab[pb]; fb = *(const float4*)(feat + pb * D + sub * 4); }
        if (va) ma = *(const float4*)(means + la * D + sub * 4);
        if (vb) mb = *(const float4*)(means + lb * D + sub * 4);
        if (va) {
            const float dx = fa.x - ma.x + EPS_F, dy = fa.y - ma.y + EPS_F;
            const float dz = fa.z - ma.z + EPS_F, dw = fa.w - ma.w + EPS_F;
            float acc = dx*dx + dy*dy + dz*dz + dw*dw;
            acc += __shfl_xor(acc, 1); acc += __shfl_xor(acc, 2); acc += __shfl_xor(acc, 4);
            if (sub == 0) {
                const float h = fmaxf(sqrtf(acc) - 1.5f, 0.f);
                racc += h * h * icnt[la];
            }
        }
        if (vb) {
            const float dx = fb.x - mb.x + EPS_F, dy = fb.y - mb.y + EPS_F;
            const float dz = fb.z - mb.z + EPS_F, dw = fb.w - mb.w + EPS_F;
            float acc = dx*dx + dy*dy + dz*dz + dw*dw;
            acc += __shfl_xor(acc, 1); acc += __shfl_xor(acc, 2); acc += __shfl_xor(acc, 4);
            if (sub == 0) {
                const float h = fmaxf(sqrtf(acc) - 1.5f, 0.f);
                racc += h * h * icnt[lb];
            }
        }
    }
    s_red[tid] = racc;
    __syncthreads();
    for (int st = 128; st; st >>= 1) { if (tid < st) s_red[tid] += s_red[tid + st]; __syncthreads(); }
    if (tid == 0) {
        atomicAdd(ws + A_RACC + (blockIdx.x & (SL - 1)), s_red[0]);
        __threadfence();                         // release (order the 2 atomics)
        s_flag = atomicAdd((int*)(ws + A_CNT) + 1, 1);
    }
    __syncthreads();
    if (s_flag != NBLK2 - 1) return;

    // ---- last block: assemble total = intra + inter + 0.001*reg ----
    __threadfence();                             // acquire
    for (int i2 = tid; i2 < K * D; i2 += 256) s_m[i2] = means[i2];
    float hs = 0.f;
    if (tid < SL) hs = ws[A_RACC + tid];
    s_red[tid] = hs;
    __syncthreads();
    for (int st = 128; st; st >>= 1) { if (tid < st) s_red[tid] += s_red[tid + st]; __syncthreads(); }
    float total = 0.f;
    if (tid == 0) total = s_red[0] * (1.0f / K);
    __syncthreads();

    // inter: thread owns column j (means[j] in regs), i rows broadcast
    float mj[32];
    const int j = tid & 63;
    {
        const float4* mrow = (const float4*)(s_m + j * D);
        #pragma unroll
        for (int q = 0; q < 8; q++) {
            const float4 t = mrow[q];
            mj[q*4+0] = t.x; mj[q*4+1] = t.y; mj[q*4+2] = t.z; mj[q*4+3] = t.w;
        }
    }
    float isum = 0.f;
    const int igrp = tid >> 6;                   // 0..3, 16 i's each
    for (int ii = 0; ii < 16; ii++) {
        const int i = igrp * 16 + ii;
        const float4* srow = (const float4*)(s_m + i * D);
        float d2 = 0.f;
        #pragma unroll
        for (int q = 0; q < 8; q++) {
            const float4 mv = srow[q];
            const float b0 = mv.x - mj[q*4+0] + EPS_F;
            const float b1 = mv.y - mj[q*4+1] + EPS_F;
            const float b2 = mv.z - mj[q*4+2] + EPS_F;
            const float b3 = mv.w - mj[q*4+3] + EPS_F;
            d2 += b0*b0 + b1*b1 + b2*b2 + b3*b3;
        }
        if (i != j) {
            const float h = fmaxf(1.0f - sqrtf(d2), 0.f);
            isum += h * h;
        }
    }
    s_red[tid] = isum;
    __syncthreads();
    for (int st = 128; st; st >>= 1) { if (tid < st) s_red[tid] += s_red[tid + st]; __syncthreads(); }
    if (tid == 0) total += s_red[0] * (1.0f / ((K - 1) * K));
    __syncthreads();

    float r = 0.f;
    if (tid < 64) {
        float d2 = 0.f;
        #pragma unroll
        for (int d = 0; d < 32; d++) { const float t = mj[d] + EPS_F; d2 += t * t; }
        r = sqrtf(d2);
    }
    s_red[tid] = r;
    __syncthreads();
    for (int st = 128; st; st >>= 1) { if (tid < st) s_red[tid] += s_red[tid + st]; __syncthreads(); }
    if (tid == 0) out[0] = total + 0.001f * (s_red[0] * (1.0f / K));
}

extern "C" void kernel_launch(void* const* d_in, const int* in_sizes, int n_in,
                              void* d_out, int out_size, void* d_ws, size_t ws_size,
                              hipStream_t stream)
{
    const float* feat = (const float*)d_in[0];
    const int*   lab  = (const int*)d_in[1];
    const int N = in_sizes[1];                   // 1e6; D=32, K=64 fixed

    float* ws = (float*)d_ws;
    const int ntiles = (N + T1 - 1) / T1;        // 3907

    hipMemsetAsync(ws, 0, ZERO_BYTES, stream);   // slices + raccs + counters
    pass1_kernel<<<ntiles, 256, 0, stream>>>(feat, lab, ws, N, ntiles);
    pass2_kernel<<<NBLK2, 256, 0, stream>>>(feat, lab, ws, (float*)d_out, N);
}

// Round 6
// 161.673 us; speedup vs baseline: 3.3261x; 3.3261x over previous
//
#include <hip/hip_runtime.h>
#include <math.h>

// DiscriminativeLoss: N=1e6 x D=32 fp32, K=64, scalar out.
// R6: revert to R4 skeleton (global atomics at per-thread volume were the
// R5 disaster: 376MB of atomic write-through). Fix pass1 divergence instead:
// equal-length sorted-walk per thread (uniform L iters, zero wave divergence)
// with register octet accumulation + rare LDS-atomic flush on cluster
// boundary (~1 lane-op/pt). pass2: 2-pt unroll + absorbs final kernel via
// last-block counter (2048 block-level atomics only).

#define EPS_F 1e-8f
constexpr int D  = 32;
constexpr int K  = 64;
constexpr int NPTS = 512;                // points per pass1 block
constexpr int PPAD = 33;                 // LDS acc pad
constexpr int P1 = K * D + K;            // 2112: 2048 sums + 64 counts
constexpr int NCH = 64;                  // reduction chunks
constexpr int NBLK2 = 2048;              // pass2 blocks (8/CU)
constexpr int SL = 8;                    // pass2 racc slices

// ws float-index layout
constexpr int A_MEANS = 0;               // K*D
constexpr int A_ICNT  = K * D;           // K
constexpr int A_RACC  = K * D + K;       // SL floats
constexpr int A_CNT   = A_RACC + SL;     // 1 int (+pad)
constexpr int A_PART2 = A_CNT + 4;       // NCH*P1
// part1 follows part2

// ---------------- pass 1: sort + equal-work sorted walk --------------------
__global__ __launch_bounds__(256) void pass1_kernel(
    const float* __restrict__ feat, const int* __restrict__ lab,
    float* __restrict__ part1, int N)
{
    __shared__ float          s_acc[K * PPAD];
    __shared__ int            s_lab[NPTS];
    __shared__ unsigned short s_idx[NPTS];
    __shared__ unsigned char  s_slab[NPTS];
    __shared__ int            s_hist[K], s_pref[K], s_cur[K];

    const int tid = threadIdx.x;
    const long long base = (long long)blockIdx.x * NPTS;
    int npts = (int)((long long)N - base);
    if (npts > NPTS) npts = NPTS;

    for (int i = tid; i < K * PPAD; i += 256) s_acc[i] = 0.f;
    if (tid < K) s_hist[tid] = 0;
    __syncthreads();

    // stage labels (int2) + histogram (1 int atomic per point)
    const int n2 = npts >> 1;
    for (int i2 = tid; i2 < n2; i2 += 256) {
        const int2 v = ((const int2*)(lab + base))[i2];
        s_lab[i2 * 2 + 0] = v.x; s_lab[i2 * 2 + 1] = v.y;
        atomicAdd(&s_hist[v.x], 1); atomicAdd(&s_hist[v.y], 1);
    }
    for (int i = (n2 << 1) + tid; i < npts; i += 256) {   // odd tail
        const int l = lab[base + i];
        s_lab[i] = l;
        atomicAdd(&s_hist[l], 1);
    }
    __syncthreads();

    // exclusive prefix over 64 bins (wave 0)
    if (tid < 64) {
        const int h = s_hist[tid];
        int v = h;
        for (int off = 1; off < 64; off <<= 1) {
            const int up = __shfl_up(v, off);
            if (tid >= off) v += up;
        }
        s_pref[tid] = v - h;
        s_cur[tid]  = v - h;
    }
    __syncthreads();

    // scatter sorted indices + sorted labels (1 int atomic per point)
    for (int i = tid; i < npts; i += 256) {
        const int l = s_lab[i];
        const int pos = atomicAdd(&s_cur[l], 1);
        s_idx[pos]  = (unsigned short)i;
        s_slab[pos] = (unsigned char)l;
    }
    __syncthreads();

    // equal-work walk: thread (seg,q) covers sorted positions [p0,p1),
    // octet q; register acc flushed to LDS on (rare) cluster boundary.
    const int q   = tid & 3;
    const int seg = tid >> 2;                 // 0..63
    const int L   = (npts + 63) >> 6;
    const int p0  = seg * L;
    int p1 = p0 + L; if (p1 > npts) p1 = npts;
    float4 a0 = {0.f,0.f,0.f,0.f}, a1 = {0.f,0.f,0.f,0.f};
    int curk = (p0 < p1) ? (int)s_slab[p0] : -1;
    for (int p = p0; p < p1; ++p) {
        const int kk = (int)s_slab[p];
        if (kk != curk) {                     // flush (rare, ~1-2 per walk)
            float* dst = s_acc + curk * PPAD + q * 8;
            atomicAdd(dst + 0, a0.x); atomicAdd(dst + 1, a0.y);
            atomicAdd(dst + 2, a0.z); atomicAdd(dst + 3, a0.w);
            atomicAdd(dst + 4, a1.x); atomicAdd(dst + 5, a1.y);
            atomicAdd(dst + 6, a1.z); atomicAdd(dst + 7, a1.w);
            a0 = {0.f,0.f,0.f,0.f}; a1 = {0.f,0.f,0.f,0.f};
            curk = kk;
        }
        const int idx = s_idx[p];
        const float4* row = (const float4*)(feat + (base + idx) * D + q * 8);
        const float4 x = row[0], y = row[1];  // 4 q-threads = full 128B line
        a0.x += x.x; a0.y += x.y; a0.z += x.z; a0.w += x.w;
        a1.x += y.x; a1.y += y.y; a1.z += y.z; a1.w += y.w;
    }
    if (curk >= 0) {
        float* dst = s_acc + curk * PPAD + q * 8;
        atomicAdd(dst + 0, a0.x); atomicAdd(dst + 1, a0.y);
        atomicAdd(dst + 2, a0.z); atomicAdd(dst + 3, a0.w);
        atomicAdd(dst + 4, a1.x); atomicAdd(dst + 5, a1.y);
        atomicAdd(dst + 6, a1.z); atomicAdd(dst + 7, a1.w);
    }
    __syncthreads();

    float* outp = part1 + (long long)blockIdx.x * P1;
    for (int e = tid; e < K * D; e += 256)
        outp[e] = s_acc[(e >> 5) * PPAD + (e & 31)];
    if (tid < K) outp[K * D + tid] = (float)s_hist[tid];
}

// ---------------- stage A: nblk1 partials -> NCH partials (coalesced) ------
__global__ __launch_bounds__(256) void reduce1_kernel(
    const float* __restrict__ part1, float* __restrict__ part2,
    int chsz, int nblk1)
{
    const int e = blockIdx.x * 256 + threadIdx.x;
    if (e >= P1) return;
    const int y = blockIdx.y;
    const int b0 = y * chsz;
    int b1 = b0 + chsz; if (b1 > nblk1) b1 = nblk1;
    float s = 0.f;
    for (int b = b0; b < b1; b++) s += part1[(long long)b * P1 + e];
    part2[(long long)y * P1 + e] = s;
}

// ---------------- stage B: NCH partials -> means, inv_counts ---------------
__global__ __launch_bounds__(256) void mean_kernel(
    const float* __restrict__ part2,
    float* __restrict__ means, float* __restrict__ icnt)
{
    const int e = blockIdx.x * blockDim.x + threadIdx.x;
    if (e >= P1) return;
    if (e < K * D) {
        float s = 0.f, c = 0.f;
        const int k = e >> 5;
        for (int y = 0; y < NCH; y++) {
            s += part2[(long long)y * P1 + e];
            c += part2[(long long)y * P1 + K * D + k];
        }
        means[e] = s / fmaxf(c, 1.0f);
    } else {
        float s = 0.f;
        for (int y = 0; y < NCH; y++) s += part2[(long long)y * P1 + e];
        icnt[e - K * D] = 1.0f / fmaxf(s, 1.0f);
    }
}

// ---------------- pass 2: hinge^2*icnt (2-pt unroll) + last-block final ----
__global__ __launch_bounds__(256, 8) void pass2_kernel(
    const float* __restrict__ feat, const int* __restrict__ lab,
    float* __restrict__ ws, float* __restrict__ out, int N)
{
    __shared__ float s_red[256];
    __shared__ float s_m[K * D];
    __shared__ int   s_flag;
    const float* means = ws + A_MEANS;
    const float* icnt  = ws + A_ICNT;
    const int tid = threadIdx.x;
    const int sub = tid & 7, g = tid >> 3;       // g in [0,32)
    float racc = 0.f;
    const long long stride = (long long)NBLK2 * 64;
    for (long long pbase = (long long)blockIdx.x * 64; pbase < N; pbase += stride) {
        const long long pa = pbase + g, pb = pbase + 32 + g;
        float4 fa, fb, ma, mb; int la = 0, lb = 0;
        const bool va = (pa < N), vb = (pb < N);
        if (va) { la = lab[pa]; fa = *(const float4*)(feat + pa * D + sub * 4); }
        if (vb) { lb = lab[pb]; fb = *(const float4*)(feat + pb * D + sub * 4); }
        if (va) ma = *(const float4*)(means + la * D + sub * 4);
        if (vb) mb = *(const float4*)(means + lb * D + sub * 4);
        if (va) {
            const float dx = fa.x - ma.x + EPS_F, dy = fa.y - ma.y + EPS_F;
            const float dz = fa.z - ma.z + EPS_F, dw = fa.w - ma.w + EPS_F;
            float acc = dx*dx + dy*dy + dz*dz + dw*dw;
            acc += __shfl_xor(acc, 1); acc += __shfl_xor(acc, 2); acc += __shfl_xor(acc, 4);
            if (sub == 0) {
                const float h = fmaxf(sqrtf(acc) - 1.5f, 0.f);
                racc += h * h * icnt[la];
            }
        }
        if (vb) {
            const float dx = fb.x - mb.x + EPS_F, dy = fb.y - mb.y + EPS_F;
            const float dz = fb.z - mb.z + EPS_F, dw = fb.w - mb.w + EPS_F;
            float acc = dx*dx + dy*dy + dz*dz + dw*dw;
            acc += __shfl_xor(acc, 1); acc += __shfl_xor(acc, 2); acc += __shfl_xor(acc, 4);
            if (sub == 0) {
                const float h = fmaxf(sqrtf(acc) - 1.5f, 0.f);
                racc += h * h * icnt[lb];
            }
        }
    }
    s_red[tid] = racc;
    __syncthreads();
    for (int st = 128; st; st >>= 1) { if (tid < st) s_red[tid] += s_red[tid + st]; __syncthreads(); }
    if (tid == 0) {
        atomicAdd(ws + A_RACC + (blockIdx.x & (SL - 1)), s_red[0]);
        __threadfence();                         // release
        s_flag = atomicAdd((int*)(ws + A_CNT), 1);
    }
    __syncthreads();
    if (s_flag != NBLK2 - 1) return;

    // ---- last block: total = intra + inter + 0.001*reg ----
    __threadfence();                             // acquire
    for (int i2 = tid; i2 < K * D; i2 += 256) s_m[i2] = means[i2];
    float hs = (tid < SL) ? ws[A_RACC + tid] : 0.f;
    s_red[tid] = hs;
    __syncthreads();
    for (int st = 128; st; st >>= 1) { if (tid < st) s_red[tid] += s_red[tid + st]; __syncthreads(); }
    float total = 0.f;
    if (tid == 0) total = s_red[0] * (1.0f / K);
    __syncthreads();

    float mj[32];
    const int j = tid & 63;
    {
        const float4* mrow = (const float4*)(s_m + j * D);
        #pragma unroll
        for (int q = 0; q < 8; q++) {
            const float4 t = mrow[q];
            mj[q*4+0] = t.x; mj[q*4+1] = t.y; mj[q*4+2] = t.z; mj[q*4+3] = t.w;
        }
    }
    float isum = 0.f;
    const int igrp = tid >> 6;                   // 0..3, 16 i's each
    for (int ii = 0; ii < 16; ii++) {
        const int i = igrp * 16 + ii;
        const float4* srow = (const float4*)(s_m + i * D);
        float d2 = 0.f;
        #pragma unroll
        for (int q = 0; q < 8; q++) {
            const float4 mv = srow[q];
            const float b0 = mv.x - mj[q*4+0] + EPS_F;
            const float b1 = mv.y - mj[q*4+1] + EPS_F;
            const float b2 = mv.z - mj[q*4+2] + EPS_F;
            const float b3 = mv.w - mj[q*4+3] + EPS_F;
            d2 += b0*b0 + b1*b1 + b2*b2 + b3*b3;
        }
        if (i != j) {
            const float h = fmaxf(1.0f - sqrtf(d2), 0.f);
            isum += h * h;
        }
    }
    s_red[tid] = isum;
    __syncthreads();
    for (int st = 128; st; st >>= 1) { if (tid < st) s_red[tid] += s_red[tid + st]; __syncthreads(); }
    if (tid == 0) total += s_red[0] * (1.0f / ((K - 1) * K));
    __syncthreads();

    float r = 0.f;
    if (tid < 64) {
        float d2 = 0.f;
        #pragma unroll
        for (int d = 0; d < 32; d++) { const float t = mj[d] + EPS_F; d2 += t * t; }
        r = sqrtf(d2);
    }
    s_red[tid] = r;
    __syncthreads();
    for (int st = 128; st; st >>= 1) { if (tid < st) s_red[tid] += s_red[tid + st]; __syncthreads(); }
    if (tid == 0) out[0] = total + 0.001f * (s_red[0] * (1.0f / K));
}

extern "C" void kernel_launch(void* const* d_in, const int* in_sizes, int n_in,
                              void* d_out, int out_size, void* d_ws, size_t ws_size,
                              hipStream_t stream)
{
    const float* feat = (const float*)d_in[0];
    const int*   lab  = (const int*)d_in[1];
    const int N = in_sizes[1];                   // 1e6; D=32, K=64 fixed

    float* ws = (float*)d_ws;
    const int nblk1 = (N + NPTS - 1) / NPTS;     // 1954
    const int chsz  = (nblk1 + NCH - 1) / NCH;   // 31

    float* means = ws + A_MEANS;
    float* icnt  = ws + A_ICNT;
    float* part2 = ws + A_PART2;
    float* part1 = part2 + (long long)NCH * P1;

    hipMemsetAsync(ws + A_RACC, 0, (SL + 4) * 4, stream);  // raccs + counter
    pass1_kernel<<<nblk1, 256, 0, stream>>>(feat, lab, part1, N);
    reduce1_kernel<<<dim3((P1 + 255) / 256, NCH), 256, 0, stream>>>(part1, part2, chsz, nblk1);
    mean_kernel<<<(P1 + 255) / 256, 256, 0, stream>>>(part2, means, icnt);
    pass2_kernel<<<NBLK2, 256, 0, stream>>>(feat, lab, ws, (float*)d_out, N);
}

// Round 7
// 69.501 us; speedup vs baseline: 7.7371x; 2.3262x over previous
//
#include <hip/hip_runtime.h>
#include <math.h>

// DiscriminativeLoss: N=1e6 x D=32 fp32, K=64, scalar out.
// R7: revert to R4 skeleton (R6's single-line returning-atomic finale cost
// ~70us of serialization tail; equal-work walk added LDS-dependency cost).
// ONE isolated change vs R4: NPTS 512 -> 1024 (cluster-run max/mean
// divergence 1.64 -> 1.45, part1 halves).

#define EPS_F 1e-8f
constexpr int D = 32;
constexpr int K = 64;
constexpr int NPTS = 1024;               // points per pass1 block (R4: 512)
constexpr int P1 = K * D + K;            // 2112: 2048 sums + 64 counts
constexpr int NCH = 64;                  // reduction chunks
constexpr int NBLK2 = 2048;              // pass2 blocks (8/CU)

// ---------------- pass 1: sort-by-label, register segment sums -------------
__global__ __launch_bounds__(256, 8) void pass1_kernel(
    const float* __restrict__ feat, const int* __restrict__ lab,
    float* __restrict__ part1, int N)
{
    __shared__ int            s_lab[NPTS];
    __shared__ unsigned short s_idx[NPTS];
    __shared__ int            s_hist[K];
    __shared__ int            s_pref[K];
    __shared__ int            s_cur[K];

    const int tid = threadIdx.x;
    const long long base = (long long)blockIdx.x * NPTS;
    int npts = (int)((long long)N - base);
    if (npts > NPTS) npts = NPTS;

    if (tid < K) s_hist[tid] = 0;
    __syncthreads();

    // stage labels (coalesced int4) + histogram (1 int atomic per point)
    const int n4 = npts >> 2;
    for (int i4 = tid; i4 < n4; i4 += 256) {
        const int4 v = ((const int4*)(lab + base))[i4];
        s_lab[i4 * 4 + 0] = v.x; s_lab[i4 * 4 + 1] = v.y;
        s_lab[i4 * 4 + 2] = v.z; s_lab[i4 * 4 + 3] = v.w;
        atomicAdd(&s_hist[v.x], 1); atomicAdd(&s_hist[v.y], 1);
        atomicAdd(&s_hist[v.z], 1); atomicAdd(&s_hist[v.w], 1);
    }
    for (int i = (n4 << 2) + tid; i < npts; i += 256) {  // tail
        const int l = lab[base + i];
        s_lab[i] = l;
        atomicAdd(&s_hist[l], 1);
    }
    __syncthreads();

    // exclusive prefix over 64 bins (wave 0)
    if (tid < 64) {
        const int h = s_hist[tid];
        int v = h;
        for (int off = 1; off < 64; off <<= 1) {
            const int up = __shfl_up(v, off);
            if (tid >= off) v += up;
        }
        s_pref[tid] = v - h;
        s_cur[tid]  = v - h;
    }
    __syncthreads();

    // scatter sorted indices (1 int atomic per point)
    for (int i = tid; i < npts; i += 256) {
        const int l = s_lab[i];
        const int pos = atomicAdd(&s_cur[l], 1);
        s_idx[pos] = (unsigned short)i;
    }
    __syncthreads();

    // register accumulation: thread owns cluster k = tid>>2, dims q*8..q*8+7
    const int k = tid >> 2, q = tid & 3;
    const int start = s_pref[k], len = s_hist[k];
    float4 a0 = {0.f, 0.f, 0.f, 0.f}, a1 = {0.f, 0.f, 0.f, 0.f};
    int i = 0;
    for (; i + 2 <= len; i += 2) {              // unroll x2: 4 loads in flight
        const int i0 = s_idx[start + i];
        const int i1 = s_idx[start + i + 1];
        const float4* r0 = (const float4*)(feat + (base + i0) * D + q * 8);
        const float4* r1 = (const float4*)(feat + (base + i1) * D + q * 8);
        const float4 x0 = r0[0], y0 = r0[1];
        const float4 x1 = r1[0], y1 = r1[1];
        a0.x += x0.x + x1.x; a0.y += x0.y + x1.y;
        a0.z += x0.z + x1.z; a0.w += x0.w + x1.w;
        a1.x += y0.x + y1.x; a1.y += y0.y + y1.y;
        a1.z += y0.z + y1.z; a1.w += y0.w + y1.w;
    }
    if (i < len) {
        const int i0 = s_idx[start + i];
        const float4* r0 = (const float4*)(feat + (base + i0) * D + q * 8);
        const float4 x0 = r0[0], y0 = r0[1];
        a0.x += x0.x; a0.y += x0.y; a0.z += x0.z; a0.w += x0.w;
        a1.x += y0.x; a1.y += y0.y; a1.z += y0.z; a1.w += y0.w;
    }
    float* outp = part1 + (long long)blockIdx.x * P1;
    ((float4*)outp)[tid * 2 + 0] = a0;        // cell k*32 + q*8 == tid*8
    ((float4*)outp)[tid * 2 + 1] = a1;
    if (tid < K) outp[K * D + tid] = (float)s_hist[tid];
}

// ---------------- stage A: nblk1 partials -> NCH partials (coalesced) ------
__global__ __launch_bounds__(256) void reduce1_kernel(
    const float* __restrict__ part1, float* __restrict__ part2,
    int chsz, int nblk1)
{
    const int e = blockIdx.x * 256 + threadIdx.x;
    if (e >= P1) return;
    const int y = blockIdx.y;
    const int b0 = y * chsz;
    int b1 = b0 + chsz; if (b1 > nblk1) b1 = nblk1;
    float s = 0.f;
    for (int b = b0; b < b1; b++) s += part1[(long long)b * P1 + e];
    part2[(long long)y * P1 + e] = s;
}

// ---------------- stage B: NCH partials -> means, inv_counts ---------------
__global__ __launch_bounds__(256) void mean_kernel(
    const float* __restrict__ part2,
    float* __restrict__ means, float* __restrict__ icnt)
{
    const int e = blockIdx.x * blockDim.x + threadIdx.x;
    if (e >= P1) return;
    if (e < K * D) {
        float s = 0.f, c = 0.f;
        const int k = e >> 5;
        for (int y = 0; y < NCH; y++) {
            s += part2[(long long)y * P1 + e];
            c += part2[(long long)y * P1 + K * D + k];
        }
        means[e] = s / fmaxf(c, 1.0f);
    } else {
        float s = 0.f;
        for (int y = 0; y < NCH; y++) s += part2[(long long)y * P1 + e];
        icnt[e - K * D] = 1.0f / fmaxf(s, 1.0f);
    }
}

// ---------------- pass 2: per-point h^2*icnt[l], register accumulation -----
__global__ __launch_bounds__(256, 8) void pass2_kernel(
    const float* __restrict__ feat, const int* __restrict__ lab,
    const float* __restrict__ means, const float* __restrict__ icnt,
    float* __restrict__ hpart, int N)
{
    __shared__ float s_red[256];
    const int tid  = threadIdx.x;
    const int sub  = tid & 7;
    const int pofs = tid >> 3;
    const long long stride = (long long)NBLK2 * 32;
    float racc = 0.f;
    for (long long p = (long long)blockIdx.x * 32 + pofs; p < N; p += stride) {
        const int l = lab[p];
        const float4 f = *(const float4*)(feat + p * D + sub * 4);
        const float4 m = *(const float4*)(means + l * D + sub * 4); // 8KB, L1
        const float dx = f.x - m.x + EPS_F;
        const float dy = f.y - m.y + EPS_F;
        const float dz = f.z - m.z + EPS_F;
        const float dw = f.w - m.w + EPS_F;
        float acc = dx * dx + dy * dy + dz * dz + dw * dw;
        acc += __shfl_xor(acc, 1);            // reduce over 8 lanes (one point)
        acc += __shfl_xor(acc, 2);
        acc += __shfl_xor(acc, 4);
        if (sub == 0) {
            const float dist = sqrtf(acc);
            const float h = fmaxf(dist - 1.5f, 0.f);   // INTRA_MARGIN_USED
            racc += h * h * icnt[l];          // no atomics: register accum
        }
    }
    s_red[tid] = racc;
    __syncthreads();
    for (int st = 128; st; st >>= 1) { if (tid < st) s_red[tid] += s_red[tid + st]; __syncthreads(); }
    if (tid == 0) hpart[blockIdx.x] = s_red[0];
}

// ---------------- final: intra-mean + inter + reg -> total -----------------
__global__ __launch_bounds__(256) void final_kernel(
    const float* __restrict__ hpart,
    const float* __restrict__ means, float* __restrict__ out)
{
    __shared__ float s_m[K * D];      // 8 KB means copy
    __shared__ float s_red[256];
    const int tid = threadIdx.x;
    for (int i = tid; i < K * D; i += 256) s_m[i] = means[i];

    // --- intra: sum 2048 block partials (= sum_k percluster), / K ---
    float hs = 0.f;
    for (int b = tid; b < NBLK2; b += 256) hs += hpart[b];
    s_red[tid] = hs;
    __syncthreads();
    for (int s = 128; s; s >>= 1) { if (tid < s) s_red[tid] += s_red[tid + s]; __syncthreads(); }
    float total = 0.f;
    if (tid == 0) total = s_red[0] * (1.0f / K);
    __syncthreads();

    // --- inter: thread owns column j (means[j] in regs), i rows broadcast ---
    float mj[32];
    const int j = tid & 63;
    {
        const float4* mrow = (const float4*)(means + j * D);
        #pragma unroll
        for (int q = 0; q < 8; q++) {
            const float4 t = mrow[q];
            mj[q * 4 + 0] = t.x; mj[q * 4 + 1] = t.y;
            mj[q * 4 + 2] = t.z; mj[q * 4 + 3] = t.w;
        }
    }
    float isum = 0.f;
    const int igrp = tid >> 6;        // 0..3, 16 i's each
    for (int ii = 0; ii < 16; ii++) {
        const int i = igrp * 16 + ii;
        const float4* srow = (const float4*)(s_m + i * D);  // wave-uniform
        float d2 = 0.f;
        #pragma unroll
        for (int q = 0; q < 8; q++) {
            const float4 mv = srow[q];
            const float a0 = mv.x - mj[q * 4 + 0] + EPS_F;
            const float a1 = mv.y - mj[q * 4 + 1] + EPS_F;
            const float a2 = mv.z - mj[q * 4 + 2] + EPS_F;
            const float a3 = mv.w - mj[q * 4 + 3] + EPS_F;
            d2 += a0 * a0 + a1 * a1 + a2 * a2 + a3 * a3;
        }
        if (i != j) {
            const float pd = sqrtf(d2);
            const float h = fmaxf(1.0f - pd, 0.f);   // 2*INTER_MARGIN_USED - pd
            isum += h * h;
        }
    }
    s_red[tid] = isum;
    __syncthreads();
    for (int s = 128; s; s >>= 1) { if (tid < s) s_red[tid] += s_red[tid + s]; __syncthreads(); }
    if (tid == 0) total += s_red[0] * (1.0f / ((K - 1) * K));
    __syncthreads();

    // --- reg: ||means[j] + EPS|| from registers (threads 0..63 only) ---
    float r = 0.f;
    if (tid < 64) {
        float d2 = 0.f;
        #pragma unroll
        for (int d = 0; d < 32; d++) { const float t = mj[d] + EPS_F; d2 += t * t; }
        r = sqrtf(d2);
    }
    s_red[tid] = r;
    __syncthreads();
    for (int s = 128; s; s >>= 1) { if (tid < s) s_red[tid] += s_red[tid + s]; __syncthreads(); }
    if (tid == 0) out[0] = total + 0.001f * (s_red[0] * (1.0f / K));
}

extern "C" void kernel_launch(void* const* d_in, const int* in_sizes, int n_in,
                              void* d_out, int out_size, void* d_ws, size_t ws_size,
                              hipStream_t stream)
{
    const float* feat = (const float*)d_in[0];
    const int*   lab  = (const int*)d_in[1];
    const int N = in_sizes[1];            // 1e6; D=32, K=64 fixed by reference

    float* ws = (float*)d_ws;

    const int nblk1 = (N + NPTS - 1) / NPTS;         // 977
    const int chsz  = (nblk1 + NCH - 1) / NCH;       // 16

    float* means = ws;                               // K*D
    float* icnt  = means + K * D;                    // K
    float* part2 = icnt + K;                         // NCH*P1
    float* hpart = part2 + (long long)NCH * P1;      // NBLK2
    float* part1 = hpart + NBLK2;                    // nblk1*P1

    pass1_kernel<<<nblk1, 256, 0, stream>>>(feat, lab, part1, N);
    reduce1_kernel<<<dim3((P1 + 255) / 256, NCH), 256, 0, stream>>>(part1, part2, chsz, nblk1);
    mean_kernel<<<(P1 + 255) / 256, 256, 0, stream>>>(part2, means, icnt);
    pass2_kernel<<<NBLK2, 256, 0, stream>>>(feat, lab, means, icnt, hpart, N);
    final_kernel<<<1, 256, 0, stream>>>(hpart, means, (float*)d_out);
}

// Round 8
// 65.762 us; speedup vs baseline: 8.1770x; 1.0569x over previous
//
#include <hip/hip_runtime.h>
#include <math.h>

// DiscriminativeLoss: N=1e6 x D=32 fp32, K=64, scalar out.
// R8 (on R7 base, 69.5us): (a) pass2 lane-owns-point: 8 independent dwordx4
// per lane (deep MLP), means+icnt staged in LDS (breaks lab->means global
// dependent chain, removes shfl reduce + sub==0 divergence). (b) pass1
// gather unroll x4. (c) inter+reg computed in pass2 block 0 epilogue
// (means globally visible pre-launch; overlaps free), final shrinks to
// hpart-sum+combine. Lessons kept: no same-line returning atomics in tails
// (R6: ~80cyc each, serializing); per-cluster register walk beats
// equal-work walk (R6).

#define EPS_F 1e-8f
constexpr int D = 32;
constexpr int K = 64;
constexpr int NPTS = 1024;               // points per pass1 block
constexpr int P1 = K * D + K;            // 2112: 2048 sums + 64 counts
constexpr int NCH = 64;                  // reduction chunks
constexpr int NBLK2 = 2048;              // pass2 blocks
constexpr int MPAD = 40;                 // LDS means row stride (16B-aligned)

// ---------------- pass 1: sort-by-label, register segment sums -------------
__global__ __launch_bounds__(256, 4) void pass1_kernel(
    const float* __restrict__ feat, const int* __restrict__ lab,
    float* __restrict__ part1, int N)
{
    __shared__ int            s_lab[NPTS];
    __shared__ unsigned short s_idx[NPTS];
    __shared__ int            s_hist[K];
    __shared__ int            s_pref[K];
    __shared__ int            s_cur[K];

    const int tid = threadIdx.x;
    const long long base = (long long)blockIdx.x * NPTS;
    int npts = (int)((long long)N - base);
    if (npts > NPTS) npts = NPTS;

    if (tid < K) s_hist[tid] = 0;
    __syncthreads();

    // stage labels (coalesced int4) + histogram (1 int atomic per point)
    const int n4 = npts >> 2;
    for (int i4 = tid; i4 < n4; i4 += 256) {
        const int4 v = ((const int4*)(lab + base))[i4];
        s_lab[i4 * 4 + 0] = v.x; s_lab[i4 * 4 + 1] = v.y;
        s_lab[i4 * 4 + 2] = v.z; s_lab[i4 * 4 + 3] = v.w;
        atomicAdd(&s_hist[v.x], 1); atomicAdd(&s_hist[v.y], 1);
        atomicAdd(&s_hist[v.z], 1); atomicAdd(&s_hist[v.w], 1);
    }
    for (int i = (n4 << 2) + tid; i < npts; i += 256) {  // tail
        const int l = lab[base + i];
        s_lab[i] = l;
        atomicAdd(&s_hist[l], 1);
    }
    __syncthreads();

    // exclusive prefix over 64 bins (wave 0)
    if (tid < 64) {
        const int h = s_hist[tid];
        int v = h;
        for (int off = 1; off < 64; off <<= 1) {
            const int up = __shfl_up(v, off);
            if (tid >= off) v += up;
        }
        s_pref[tid] = v - h;
        s_cur[tid]  = v - h;
    }
    __syncthreads();

    // scatter sorted indices (1 int atomic per point)
    for (int i = tid; i < npts; i += 256) {
        const int l = s_lab[i];
        const int pos = atomicAdd(&s_cur[l], 1);
        s_idx[pos] = (unsigned short)i;
    }
    __syncthreads();

    // register accumulation: thread owns cluster k = tid>>2, dims q*8..q*8+7
    const int k = tid >> 2, q = tid & 3;
    const int start = s_pref[k], len = s_hist[k];
    float4 a0 = {0.f, 0.f, 0.f, 0.f}, a1 = {0.f, 0.f, 0.f, 0.f};
    int i = 0;
    for (; i + 4 <= len; i += 4) {            // unroll x4: 8 loads in flight
        const int i0 = s_idx[start + i + 0];
        const int i1 = s_idx[start + i + 1];
        const int i2 = s_idx[start + i + 2];
        const int i3 = s_idx[start + i + 3];
        const float4* r0 = (const float4*)(feat + (base + i0) * D + q * 8);
        const float4* r1 = (const float4*)(feat + (base + i1) * D + q * 8);
        const float4* r2 = (const float4*)(feat + (base + i2) * D + q * 8);
        const float4* r3 = (const float4*)(feat + (base + i3) * D + q * 8);
        const float4 x0 = r0[0], y0 = r0[1];
        const float4 x1 = r1[0], y1 = r1[1];
        const float4 x2 = r2[0], y2 = r2[1];
        const float4 x3 = r3[0], y3 = r3[1];
        a0.x += (x0.x + x1.x) + (x2.x + x3.x);
        a0.y += (x0.y + x1.y) + (x2.y + x3.y);
        a0.z += (x0.z + x1.z) + (x2.z + x3.z);
        a0.w += (x0.w + x1.w) + (x2.w + x3.w);
        a1.x += (y0.x + y1.x) + (y2.x + y3.x);
        a1.y += (y0.y + y1.y) + (y2.y + y3.y);
        a1.z += (y0.z + y1.z) + (y2.z + y3.z);
        a1.w += (y0.w + y1.w) + (y2.w + y3.w);
    }
    for (; i < len; ++i) {
        const int i0 = s_idx[start + i];
        const float4* r0 = (const float4*)(feat + (base + i0) * D + q * 8);
        const float4 x0 = r0[0], y0 = r0[1];
        a0.x += x0.x; a0.y += x0.y; a0.z += x0.z; a0.w += x0.w;
        a1.x += y0.x; a1.y += y0.y; a1.z += y0.z; a1.w += y0.w;
    }
    float* outp = part1 + (long long)blockIdx.x * P1;
    ((float4*)outp)[tid * 2 + 0] = a0;        // cell k*32 + q*8 == tid*8
    ((float4*)outp)[tid * 2 + 1] = a1;
    if (tid < K) outp[K * D + tid] = (float)s_hist[tid];
}

// ---------------- stage A: nblk1 partials -> NCH partials (coalesced) ------
__global__ __launch_bounds__(256) void reduce1_kernel(
    const float* __restrict__ part1, float* __restrict__ part2,
    int chsz, int nblk1)
{
    const int e = blockIdx.x * 256 + threadIdx.x;
    if (e >= P1) return;
    const int y = blockIdx.y;
    const int b0 = y * chsz;
    int b1 = b0 + chsz; if (b1 > nblk1) b1 = nblk1;
    float s = 0.f;
    for (int b = b0; b < b1; b++) s += part1[(long long)b * P1 + e];
    part2[(long long)y * P1 + e] = s;
}

// ---------------- stage B: NCH partials -> means, inv_counts ---------------
__global__ __launch_bounds__(256) void mean_kernel(
    const float* __restrict__ part2,
    float* __restrict__ means, float* __restrict__ icnt)
{
    const int e = blockIdx.x * blockDim.x + threadIdx.x;
    if (e >= P1) return;
    if (e < K * D) {
        float s = 0.f, c = 0.f;
        const int k = e >> 5;
        for (int y = 0; y < NCH; y++) {
            s += part2[(long long)y * P1 + e];
            c += part2[(long long)y * P1 + K * D + k];
        }
        means[e] = s / fmaxf(c, 1.0f);
    } else {
        float s = 0.f;
        for (int y = 0; y < NCH; y++) s += part2[(long long)y * P1 + e];
        icnt[e - K * D] = 1.0f / fmaxf(s, 1.0f);
    }
}

// ---------------- pass 2: lane-owns-point hinge + block0 inter/reg ---------
__global__ __launch_bounds__(256, 4) void pass2_kernel(
    const float* __restrict__ feat, const int* __restrict__ lab,
    const float* __restrict__ means, const float* __restrict__ icnt,
    float* __restrict__ hpart, float* __restrict__ ir, int N)
{
    __shared__ float s_m[K * MPAD];   // padded means, 10 KB
    __shared__ float s_ic[K];
    __shared__ float s_red[256];
    const int tid = threadIdx.x;

    for (int e = tid; e < K * D; e += 256)        // coalesced global read,
        s_m[(e >> 5) * MPAD + (e & 31)] = means[e]; // scalar LDS writes
    if (tid < K) s_ic[tid] = icnt[tid];
    __syncthreads();

    float racc = 0.f;
    const long long stride = (long long)NBLK2 * 256;
    for (long long p = (long long)blockIdx.x * 256 + tid; p < N; p += stride) {
        const int l = lab[p];
        const float4* frow = (const float4*)(feat + p * D);
        float4 fv[8];
        #pragma unroll
        for (int j = 0; j < 8; j++) fv[j] = frow[j];   // 8 loads in flight
        const float* mrow = s_m + l * MPAD;
        float d2 = 0.f;
        #pragma unroll
        for (int j = 0; j < 8; j++) {
            const float4 mv = *(const float4*)(mrow + j * 4);
            const float dx = fv[j].x - mv.x + EPS_F;
            const float dy = fv[j].y - mv.y + EPS_F;
            const float dz = fv[j].z - mv.z + EPS_F;
            const float dw = fv[j].w - mv.w + EPS_F;
            d2 += dx * dx + dy * dy + dz * dz + dw * dw;
        }
        const float h = fmaxf(sqrtf(d2) - 1.5f, 0.f);  // INTRA_MARGIN_USED
        racc += h * h * s_ic[l];
    }
    s_red[tid] = racc;
    __syncthreads();
    for (int st = 128; st; st >>= 1) { if (tid < st) s_red[tid] += s_red[tid + st]; __syncthreads(); }
    if (tid == 0) hpart[blockIdx.x] = s_red[0];

    if (blockIdx.x != 0) return;
    // ---- block 0 epilogue: inter + reg from s_m (overlaps other blocks) ----
    __syncthreads();
    float mj[32];
    const int j = tid & 63;
    #pragma unroll
    for (int d = 0; d < 32; d++) mj[d] = s_m[j * MPAD + d];
    float isum = 0.f;
    const int igrp = tid >> 6;        // 0..3, 16 i's each; i wave-uniform
    for (int ii = 0; ii < 16; ii++) {
        const int i = igrp * 16 + ii;
        const float4* srow = (const float4*)(s_m + i * MPAD);
        float d2 = 0.f;
        #pragma unroll
        for (int q = 0; q < 8; q++) {
            const float4 mv = srow[q];
            const float b0 = mv.x - mj[q * 4 + 0] + EPS_F;
            const float b1 = mv.y - mj[q * 4 + 1] + EPS_F;
            const float b2 = mv.z - mj[q * 4 + 2] + EPS_F;
            const float b3 = mv.w - mj[q * 4 + 3] + EPS_F;
            d2 += b0 * b0 + b1 * b1 + b2 * b2 + b3 * b3;
        }
        if (i != j) {
            const float h = fmaxf(1.0f - sqrtf(d2), 0.f);  // 2*margin - pd
            isum += h * h;
        }
    }
    s_red[tid] = isum;
    __syncthreads();
    for (int st = 128; st; st >>= 1) { if (tid < st) s_red[tid] += s_red[tid + st]; __syncthreads(); }
    if (tid == 0) ir[0] = s_red[0] * (1.0f / ((K - 1) * K));
    __syncthreads();

    float r = 0.f;
    if (tid < 64) {
        float d2 = 0.f;
        #pragma unroll
        for (int d = 0; d < 32; d++) { const float t = mj[d] + EPS_F; d2 += t * t; }
        r = sqrtf(d2);
    }
    s_red[tid] = r;
    __syncthreads();
    for (int st = 128; st; st >>= 1) { if (tid < st) s_red[tid] += s_red[tid + st]; __syncthreads(); }
    if (tid == 0) ir[1] = s_red[0] * (1.0f / K);
}

// ---------------- final: hpart sum + combine --------------------------------
__global__ __launch_bounds__(256) void final_kernel(
    const float* __restrict__ hpart, const float* __restrict__ ir,
    float* __restrict__ out)
{
    __shared__ float s_red[256];
    const int tid = threadIdx.x;
    float hs = 0.f;
    for (int b = tid; b < NBLK2; b += 256) hs += hpart[b];
    s_red[tid] = hs;
    __syncthreads();
    for (int st = 128; st; st >>= 1) { if (tid < st) s_red[tid] += s_red[tid + st]; __syncthreads(); }
    if (tid == 0) out[0] = s_red[0] * (1.0f / K) + ir[0] + 0.001f * ir[1];
}

extern "C" void kernel_launch(void* const* d_in, const int* in_sizes, int n_in,
                              void* d_out, int out_size, void* d_ws, size_t ws_size,
                              hipStream_t stream)
{
    const float* feat = (const float*)d_in[0];
    const int*   lab  = (const int*)d_in[1];
    const int N = in_sizes[1];            // 1e6; D=32, K=64 fixed by reference

    float* ws = (float*)d_ws;

    const int nblk1 = (N + NPTS - 1) / NPTS;         // 977
    const int chsz  = (nblk1 + NCH - 1) / NCH;       // 16

    float* means = ws;                               // K*D
    float* icnt  = means + K * D;                    // K
    float* ir    = icnt + K;                         // 2 (+pad 2)
    float* part2 = ir + 4;                           // NCH*P1
    float* hpart = part2 + (long long)NCH * P1;      // NBLK2
    float* part1 = hpart + NBLK2;                    // nblk1*P1

    pass1_kernel<<<nblk1, 256, 0, stream>>>(feat, lab, part1, N);
    reduce1_kernel<<<dim3((P1 + 255) / 256, NCH), 256, 0, stream>>>(part1, part2, chsz, nblk1);
    mean_kernel<<<(P1 + 255) / 256, 256, 0, stream>>>(part2, means, icnt);
    pass2_kernel<<<NBLK2, 256, 0, stream>>>(feat, lab, means, icnt, hpart, ir, N);
    final_kernel<<<1, 256, 0, stream>>>(hpart, ir, (float*)d_out);
}